// Round 2
// baseline (370.400 us; speedup 1.0000x reference)
//
#include <hip/hip_runtime.h>
#include <math.h>

// HarmonicCQT: out[b, 1, t, k] = |sum_n frame(b,t)[n] * (kr[k,n] + i*ki[k,n])|
// frames are the n_max samples ending at sample (t+1)*HOP (left zero-pad).
//
// One wave per (b, 8-frame tile, 4-bin group). Lane = n-offset in a 64-wide
// chunk. Register tile 8x4 (x2 re/im) accumulators; all global loads
// coalesced with wave-uniform bases. Structural zeros of short
// (high-frequency) kernel rows are skipped via a computed start; chunks where
// all 8 frames are still in the left zero-pad are skipped entirely.
//
// n_max (kernel row length) is derived at launch from in_sizes[1]/168 —
// the reference comment's value (23014) disagrees with the exact formula
// (23013), so we never hardcode it.

namespace {
constexpr int kSR    = 22050;
constexpr int kHop   = 512;
constexpr int kBins  = 168;
constexpr int kT     = 689;    // 352768 / 512 exactly
constexpr int kB     = 4;
constexpr int kS     = 352768;
constexpr int TT = 8;   // frames per wave
constexpr int KG = 4;   // bins per wave
constexpr int kTTiles  = (kT + TT - 1) / TT;  // 87
constexpr int kKGroups = kBins / KG;          // 42
constexpr int kWaves   = kB * kTTiles * kKGroups;  // 14616
}

__global__ __launch_bounds__(256) void cqt_mag_kernel(
    const float* __restrict__ x,
    const float* __restrict__ kr,
    const float* __restrict__ ki,
    float* __restrict__ out,
    const int nmax,          // kernel row length (runtime-derived)
    const int pad) {         // nmax - kHop
  const int wave = (blockIdx.x << 2) + (threadIdx.x >> 6);
  const int lane = threadIdx.x & 63;
  if (wave >= kWaves) return;

  // Consecutive waves share the same bin group (kernel rows hot in L2).
  const int kg    = wave / (kB * kTTiles);
  const int rem   = wave - kg * (kB * kTTiles);
  const int b     = rem / kTTiles;
  const int ttile = rem - b * kTTiles;
  const int k0 = kg * KG;
  const int t0 = ttile * TT;

  // Longest kernel in this group is bin k0 (bins ascend in freq, lengths
  // descend). +8 margin guards fp rounding; extra elements read are exact
  // zeros in the padded kernel arrays. This only controls SKIPPING.
  const double Q  = 1.0 / (exp2(1.0 / 24.0) - 1.0);
  const double f0 = 32.7 * exp2((double)k0 / 24.0);
  int N = (int)ceil(Q * (double)kSR / f0) + 8;
  int full_start = nmax - N;
  if (full_start < 0) full_start = 0;

  int tbase[TT];   // audio index = tbase[tt] + nn
  int lo[TT];      // audio valid (idx >= 0) iff nn >= lo[tt]
  int t_last;
  {
    int t = t0 + TT - 1; if (t > kT - 1) t = kT - 1;
    t_last = t;
  }
  #pragma unroll
  for (int tt = 0; tt < TT; ++tt) {
    int t = t0 + tt; if (t > kT - 1) t = kT - 1;   // clamp (dup compute, store-guarded)
    tbase[tt] = b * kS + t * kHop - pad;
    lo[tt]    = pad - t * kHop;
  }

  // Below head_start every frame's audio is in the zero pad OR the kernel is
  // structurally zero -> skip entirely.
  int head_start = pad - t_last * kHop;
  if (head_start < full_start) head_start = full_start;
  // From `safe` upward, ALL frames have valid (non-pad) audio indices.
  int safe = pad - t0 * kHop;
  if (safe < head_start) safe = head_start;
  // Align body so (nmax - body_start) % 64 == 0 -> no tail guard needed.
  int body_start = nmax - ((nmax - safe) & ~63);

  float accr[TT][KG];
  float acci[TT][KG];
  #pragma unroll
  for (int tt = 0; tt < TT; ++tt)
    #pragma unroll
    for (int kk = 0; kk < KG; ++kk) { accr[tt][kk] = 0.f; acci[tt][kk] = 0.f; }

  // ---- head: guarded (pad boundary region) ----
  for (int n = body_start - 64; n > head_start - 64; n -= 64) {
    const int nn = n + lane;
    const bool kok = (nn >= 0);
    float krv[KG], kiv[KG];
    #pragma unroll
    for (int kk = 0; kk < KG; ++kk) {
      krv[kk] = kok ? kr[(k0 + kk) * nmax + nn] : 0.f;
      kiv[kk] = kok ? ki[(k0 + kk) * nmax + nn] : 0.f;
    }
    float a[TT];
    #pragma unroll
    for (int tt = 0; tt < TT; ++tt)
      a[tt] = (nn >= lo[tt]) ? x[tbase[tt] + nn] : 0.f;
    #pragma unroll
    for (int tt = 0; tt < TT; ++tt)
      #pragma unroll
      for (int kk = 0; kk < KG; ++kk) {
        accr[tt][kk] = fmaf(a[tt], krv[kk], accr[tt][kk]);
        acci[tt][kk] = fmaf(a[tt], kiv[kk], acci[tt][kk]);
      }
  }

  // ---- body: unguarded hot loop ----
  for (int n = body_start; n < nmax; n += 64) {
    const int nn = n + lane;
    float krv[KG], kiv[KG];
    #pragma unroll
    for (int kk = 0; kk < KG; ++kk) {
      krv[kk] = kr[(k0 + kk) * nmax + nn];
      kiv[kk] = ki[(k0 + kk) * nmax + nn];
    }
    float a[TT];
    #pragma unroll
    for (int tt = 0; tt < TT; ++tt)
      a[tt] = x[tbase[tt] + nn];
    #pragma unroll
    for (int tt = 0; tt < TT; ++tt)
      #pragma unroll
      for (int kk = 0; kk < KG; ++kk) {
        accr[tt][kk] = fmaf(a[tt], krv[kk], accr[tt][kk]);
        acci[tt][kk] = fmaf(a[tt], kiv[kk], acci[tt][kk]);
      }
  }

  // ---- 64-lane butterfly reduction + store ----
  #pragma unroll
  for (int tt = 0; tt < TT; ++tt) {
    #pragma unroll
    for (int kk = 0; kk < KG; ++kk) {
      float r = accr[tt][kk];
      float i = acci[tt][kk];
      #pragma unroll
      for (int s = 32; s > 0; s >>= 1) {
        r += __shfl_xor(r, s, 64);
        i += __shfl_xor(i, s, 64);
      }
      if (lane == 0) {
        const int t = t0 + tt;
        if (t < kT)
          out[(b * kT + t) * kBins + (k0 + kk)] = sqrtf(r * r + i * i);
      }
    }
  }
}

extern "C" void kernel_launch(void* const* d_in, const int* in_sizes, int n_in,
                              void* d_out, int out_size, void* d_ws, size_t ws_size,
                              hipStream_t stream) {
  const float* x  = (const float*)d_in[0];   // [4, 1, 352768]
  const float* kr = (const float*)d_in[1];   // [168, n_max]
  const float* ki = (const float*)d_in[2];   // [168, n_max]
  float* out = (float*)d_out;                // [4, 1, 689, 168]

  const int nmax = in_sizes[1] / kBins;      // runtime truth (23013, not 23014)
  const int pad  = nmax - kHop;

  const int blocks = kWaves / 4;  // 3654 blocks, 4 waves each
  cqt_mag_kernel<<<blocks, 256, 0, stream>>>(x, kr, ki, out, nmax, pad);
}

// Round 3
// 224.645 us; speedup vs baseline: 1.6488x; 1.6488x over previous
//
#include <hip/hip_runtime.h>
#include <math.h>

// HarmonicCQT via f16 MFMA: out[b,t,k] = |sum_n xpad[t*512+n] * (kr[k,n]+i*ki[k,n])|
//
// Pipeline (all on `stream`, graph-capture safe):
//   1. hipMemsetAsync: zero split-K accumulator in ws
//   2. prep_x_kernel : fp32 audio -> zero-padded f16 xp in ws
//   3. cqt_mfma_kernel: split-K MFMA GEMM, fp32 atomics into accumulator
//   4. cqt_mag_final : sqrt(re^2+im^2) -> out
//
// Kernels are pre-scaled x4096 at f16 conversion (values ~1e-4 would be f16
// subnormals), un-scaled at the epilogue. MFMA fragment layouts (16x16x32):
//   A[m=lane&15][k=(lane>>4)*8+j],  B[k=(lane>>4)*8+j][n=lane&15],
//   C/D: col=lane&15, row=(lane>>4)*4+reg.
// Falls back to the verified fp32 kernel if ws_size is too small.

namespace {
constexpr int kSR    = 22050;
constexpr int kHop   = 512;
constexpr int kBins  = 168;
constexpr int kT     = 689;
constexpr int kB     = 4;
constexpr int kS     = 352768;
constexpr int kTPad  = 768;    // frames padded to 3 fblocks of 256
constexpr int kBinPad = 176;   // 11 groups of 16
constexpr float kKScale    = 4096.0f;
constexpr float kKScaleInv = 1.0f / 4096.0f;
}

typedef _Float16 half8 __attribute__((ext_vector_type(8)));
typedef _Float16 half2v __attribute__((ext_vector_type(2)));
typedef float floatx4 __attribute__((ext_vector_type(4)));

struct Jobs {
  int k0[48];
  int lo[48];
  int hi[48];
  int n;
};

__device__ inline void atomAddF(float* p, float v) {
  __hip_atomic_fetch_add(p, v, __ATOMIC_RELAXED, __HIP_MEMORY_SCOPE_AGENT);
}

// ---- pre-pass: padded f16 audio ----
__global__ __launch_bounds__(256) void prep_x_kernel(
    const float* __restrict__ x, _Float16* __restrict__ xp,
    const int pad, const int xps) {
  const int halfx = xps >> 1;
  int gid = blockIdx.x * 256 + threadIdx.x;
  if (gid >= kB * halfx) return;
  const int b = gid / halfx;
  const int i = (gid - b * halfx) * 2;
  float v0 = 0.f, v1 = 0.f;
  const int e0 = i, e1 = i + 1;
  if (e0 >= pad && e0 < pad + kS) v0 = x[(size_t)b * kS + (e0 - pad)];
  if (e1 >= pad && e1 < pad + kS) v1 = x[(size_t)b * kS + (e1 - pad)];
  half2v h;
  h.x = (_Float16)v0;
  h.y = (_Float16)v1;
  *(half2v*)&xp[(size_t)b * xps + i] = h;
}

// ---- main: split-K MFMA GEMM ----
__global__ __launch_bounds__(256) void cqt_mfma_kernel(
    const float* __restrict__ kr, const float* __restrict__ ki,
    const _Float16* __restrict__ xp, float* __restrict__ accb,
    const int nmax, const int xps, const Jobs jt) {
  __shared__ _Float16 Bs[2][16][264];   // +8 pad: row stride 528 B -> no bank conflicts

  const int jb = blockIdx.x;
  const int k0   = jt.k0[jb];
  const int n_lo = jt.lo[jb];
  const int n_hi = jt.hi[jb];
  const int b  = blockIdx.z;
  const int fb = blockIdx.y;

  const int tid  = threadIdx.x;
  const int lane = tid & 63;
  const int wave = tid >> 6;
  const int m = lane & 15;      // A row / D col-group
  const int q = lane >> 4;      // quad

  // staging role: thread -> (bin, strided col)
  const int sbin = tid >> 4;    // 0..15
  const int scol = tid & 15;    // 0..15
  const int gbin = k0 + sbin;
  const bool binok = (gbin < kBins);
  const float* rowr = kr + (size_t)gbin * nmax;
  const float* rowi = ki + (size_t)gbin * nmax;

  const int fbase = fb * 256 + wave * 64;
  const _Float16* ax =
      xp + (size_t)b * xps + (size_t)(fbase + m) * kHop + q * 8;

  floatx4 accr[4], acci[4];
  #pragma unroll
  for (int tl = 0; tl < 4; ++tl) {
    accr[tl] = (floatx4){0.f, 0.f, 0.f, 0.f};
    acci[tl] = (floatx4){0.f, 0.f, 0.f, 0.f};
  }

  for (int n0r = n_lo; n0r < n_hi; n0r += 256) {
    __syncthreads();   // protect previous round's Bs readers
    #pragma unroll
    for (int c = 0; c < 16; ++c) {
      const int col = n0r + scol + c * 16;        // lanes -> contiguous cols
      const bool ok = binok && (col < nmax);
      const float vr = ok ? rowr[col] : 0.f;
      const float vi = ok ? rowi[col] : 0.f;
      Bs[0][sbin][scol + c * 16] = (_Float16)(vr * kKScale);
      Bs[1][sbin][scol + c * 16] = (_Float16)(vi * kKScale);
    }
    __syncthreads();

    const _Float16* axr = ax + n0r;
    #pragma unroll
    for (int c = 0; c < 8; ++c) {
      const int ko = c * 32 + q * 8;
      const half8 br = *(const half8*)&Bs[0][m][ko];
      const half8 bi = *(const half8*)&Bs[1][m][ko];
      #pragma unroll
      for (int tl = 0; tl < 4; ++tl) {
        const half8 a = *(const half8*)(axr + tl * 16 * kHop + c * 32);
        accr[tl] = __builtin_amdgcn_mfma_f32_16x16x32_f16(a, br, accr[tl], 0, 0, 0);
        acci[tl] = __builtin_amdgcn_mfma_f32_16x16x32_f16(a, bi, acci[tl], 0, 0, 0);
      }
    }
  }

  // epilogue: un-scale + split-K atomic combine
  #pragma unroll
  for (int tl = 0; tl < 4; ++tl) {
    #pragma unroll
    for (int r = 0; r < 4; ++r) {
      const int t = fbase + tl * 16 + q * 4 + r;   // D row
      const size_t o = (((size_t)b * kTPad + t) * kBinPad + (k0 + m)) * 2;
      atomAddF(&accb[o],     accr[tl][r] * kKScaleInv);
      atomAddF(&accb[o + 1], acci[tl][r] * kKScaleInv);
    }
  }
}

// ---- final: magnitude ----
__global__ __launch_bounds__(256) void cqt_mag_final(
    const float* __restrict__ accb, float* __restrict__ out) {
  int gid = blockIdx.x * 256 + threadIdx.x;
  if (gid >= kB * kT * kBins) return;
  const int k = gid % kBins;
  const int r = gid / kBins;
  const int t = r % kT;
  const int b = r / kT;
  const float2 v = ((const float2*)accb)[((size_t)b * kTPad + t) * kBinPad + k];
  out[gid] = sqrtf(v.x * v.x + v.y * v.y);
}

// ================= fallback: verified fp32 kernel (round 2) =================
namespace fb32 {
constexpr int TT = 8;
constexpr int KG = 4;
constexpr int kTTiles  = (kT + TT - 1) / TT;
constexpr int kKGroups = kBins / KG;
constexpr int kWaves   = kB * kTTiles * kKGroups;
}

__global__ __launch_bounds__(256) void cqt_mag_kernel(
    const float* __restrict__ x,
    const float* __restrict__ kr,
    const float* __restrict__ ki,
    float* __restrict__ out,
    const int nmax, const int pad) {
  using namespace fb32;
  const int wave = (blockIdx.x << 2) + (threadIdx.x >> 6);
  const int lane = threadIdx.x & 63;
  if (wave >= kWaves) return;
  const int kg    = wave / (kB * kTTiles);
  const int rem   = wave - kg * (kB * kTTiles);
  const int b     = rem / kTTiles;
  const int ttile = rem - b * kTTiles;
  const int k0 = kg * KG;
  const int t0 = ttile * TT;
  const double Q  = 1.0 / (exp2(1.0 / 24.0) - 1.0);
  const double f0 = 32.7 * exp2((double)k0 / 24.0);
  int N = (int)ceil(Q * (double)kSR / f0) + 8;
  int full_start = nmax - N;
  if (full_start < 0) full_start = 0;
  int tbase[TT], lo[TT], t_last;
  { int t = t0 + TT - 1; if (t > kT - 1) t = kT - 1; t_last = t; }
  #pragma unroll
  for (int tt = 0; tt < TT; ++tt) {
    int t = t0 + tt; if (t > kT - 1) t = kT - 1;
    tbase[tt] = b * kS + t * kHop - pad;
    lo[tt]    = pad - t * kHop;
  }
  int head_start = pad - t_last * kHop;
  if (head_start < full_start) head_start = full_start;
  int safe = pad - t0 * kHop;
  if (safe < head_start) safe = head_start;
  int body_start = nmax - ((nmax - safe) & ~63);
  float accr[TT][KG], acci[TT][KG];
  #pragma unroll
  for (int tt = 0; tt < TT; ++tt)
    #pragma unroll
    for (int kk = 0; kk < KG; ++kk) { accr[tt][kk] = 0.f; acci[tt][kk] = 0.f; }
  for (int n = body_start - 64; n > head_start - 64; n -= 64) {
    const int nn = n + lane;
    const bool kok = (nn >= 0);
    float krv[KG], kiv[KG];
    #pragma unroll
    for (int kk = 0; kk < KG; ++kk) {
      krv[kk] = kok ? kr[(k0 + kk) * nmax + nn] : 0.f;
      kiv[kk] = kok ? ki[(k0 + kk) * nmax + nn] : 0.f;
    }
    float a[TT];
    #pragma unroll
    for (int tt = 0; tt < TT; ++tt)
      a[tt] = (nn >= lo[tt]) ? x[tbase[tt] + nn] : 0.f;
    #pragma unroll
    for (int tt = 0; tt < TT; ++tt)
      #pragma unroll
      for (int kk = 0; kk < KG; ++kk) {
        accr[tt][kk] = fmaf(a[tt], krv[kk], accr[tt][kk]);
        acci[tt][kk] = fmaf(a[tt], kiv[kk], acci[tt][kk]);
      }
  }
  for (int n = body_start; n < nmax; n += 64) {
    const int nn = n + lane;
    float krv[KG], kiv[KG];
    #pragma unroll
    for (int kk = 0; kk < KG; ++kk) {
      krv[kk] = kr[(k0 + kk) * nmax + nn];
      kiv[kk] = ki[(k0 + kk) * nmax + nn];
    }
    float a[TT];
    #pragma unroll
    for (int tt = 0; tt < TT; ++tt)
      a[tt] = x[tbase[tt] + nn];
    #pragma unroll
    for (int tt = 0; tt < TT; ++tt)
      #pragma unroll
      for (int kk = 0; kk < KG; ++kk) {
        accr[tt][kk] = fmaf(a[tt], krv[kk], accr[tt][kk]);
        acci[tt][kk] = fmaf(a[tt], kiv[kk], acci[tt][kk]);
      }
  }
  #pragma unroll
  for (int tt = 0; tt < TT; ++tt) {
    #pragma unroll
    for (int kk = 0; kk < KG; ++kk) {
      float r = accr[tt][kk];
      float i = acci[tt][kk];
      #pragma unroll
      for (int s = 32; s > 0; s >>= 1) {
        r += __shfl_xor(r, s, 64);
        i += __shfl_xor(i, s, 64);
      }
      if (lane == 0) {
        const int t = t0 + tt;
        if (t < kT)
          out[(b * kT + t) * kBins + (k0 + kk)] = sqrtf(r * r + i * i);
      }
    }
  }
}
// ============================================================================

extern "C" void kernel_launch(void* const* d_in, const int* in_sizes, int n_in,
                              void* d_out, int out_size, void* d_ws, size_t ws_size,
                              hipStream_t stream) {
  const float* x  = (const float*)d_in[0];   // [4, 1, 352768]
  const float* kr = (const float*)d_in[1];   // [168, nmax]
  const float* ki = (const float*)d_in[2];   // [168, nmax]
  float* out = (float*)d_out;                // [4, 1, 689, 168]

  const int nmax = in_sizes[1] / kBins;      // 23013 (runtime truth)
  const int pad  = nmax - kHop;

  // ws layout
  const int kcap = ((nmax + 255) / 256) * 256;              // 23040
  const int xps  = (kTPad - 1) * kHop + kcap + 256;         // padded audio len/b
  const size_t xp_bytes  = (size_t)kB * xps * sizeof(_Float16);
  const size_t acc_off   = (xp_bytes + 511) & ~(size_t)511;
  const size_t acc_bytes = (size_t)kB * kTPad * kBinPad * 2 * sizeof(float);
  const size_t ws_needed = acc_off + acc_bytes;

  if (ws_size < ws_needed) {
    // fallback: verified fp32 path (~370 us)
    const int blocks = fb32::kWaves / 4;
    cqt_mag_kernel<<<blocks, 256, 0, stream>>>(x, kr, ki, out, nmax, pad);
    return;
  }

  _Float16* xp = (_Float16*)d_ws;
  float* accb  = (float*)((char*)d_ws + acc_off);

  // job table: per 16-bin group, 2048-wide K slabs covering the non-zero support
  Jobs jt;
  int nj = 0;
  const double Q = 1.0 / (exp2(1.0 / 24.0) - 1.0);
  for (int g = 0; g < 11; ++g) {
    const int gk0 = 16 * g;
    const double f0 = 32.7 * exp2((double)gk0 / 24.0);
    const int N = (int)ceil(Q * (double)kSR / f0) + 8;
    int lo = nmax - N;
    if (lo < 0) lo = 0;
    lo = (lo / 2048) * 2048;
    for (int s = lo; s < kcap && nj < 48; s += 2048) {
      jt.k0[nj] = gk0;
      jt.lo[nj] = s;
      jt.hi[nj] = (s + 2048 < kcap) ? s + 2048 : kcap;
      ++nj;
    }
  }
  jt.n = nj;   // 42 expected

  hipMemsetAsync(accb, 0, acc_bytes, stream);

  {
    const int total = kB * (xps / 2);
    prep_x_kernel<<<(total + 255) / 256, 256, 0, stream>>>(x, xp, pad, xps);
  }

  {
    dim3 grid(nj, kTPad / 256, kB);   // (42, 3, 4)
    cqt_mfma_kernel<<<grid, 256, 0, stream>>>(kr, ki, xp, accb, nmax, xps, jt);
  }

  {
    const int total = kB * kT * kBins;
    cqt_mag_final<<<(total + 255) / 256, 256, 0, stream>>>(accb, out);
  }
}

// Round 4
// 172.727 us; speedup vs baseline: 2.1444x; 1.3006x over previous
//
#include <hip/hip_runtime.h>
#include <math.h>

// HarmonicCQT via f16 MFMA: out[b,t,k] = |sum_n xpad[t*512+n] * (kr[k,n]+i*ki[k,n])|
//
// Path A (ws >= ~13.3MB):
//   1. hipMemsetAsync: zero split-K fp32 accumulator
//   2. prep_x_kernel    : fp32 audio -> zero-padded f16 xp
//   3. prep_bpack_kernel: fp32 kernels -> f16 B-fragments in exact MFMA lane
//                         order (x4096 pre-scale), support-trimmed per job
//   4. cqt_mfma2_kernel : barrier-free, LDS-free K-loop — per 32-K chunk:
//                         2x16B B loads + 4x16B A loads + 8 MFMAs
//   5. cqt_mag_final    : sqrt(re^2+im^2)
// Path B (ws >= ~7.7MB): round-3 LDS-staging MFMA kernel (verified, ~224us).
// Path C: verified fp32 kernel (~370us).
//
// MFMA 16x16x32 layouts (verified round 3, absmax 4.9e-4):
//   A[m=lane&15][k=(lane>>4)*8+j], B[k=(lane>>4)*8+j][n=lane&15],
//   C/D: col=lane&15, row=(lane>>4)*4+reg.

namespace {
constexpr int kSR    = 22050;
constexpr int kHop   = 512;
constexpr int kBins  = 168;
constexpr int kT     = 689;
constexpr int kB     = 4;
constexpr int kS     = 352768;
constexpr int kTPad  = 768;    // frames padded to 3 fblocks of 256
constexpr int kBinPad = 176;   // 11 groups of 16
constexpr float kKScale    = 4096.0f;
constexpr float kKScaleInv = 1.0f / 4096.0f;
}

typedef _Float16 half8 __attribute__((ext_vector_type(8)));
typedef _Float16 half2v __attribute__((ext_vector_type(2)));
typedef float floatx4 __attribute__((ext_vector_type(4)));

struct Jobs {          // path B job table
  int k0[48];
  int lo[48];
  int hi[48];
  int n;
};

struct Jobs2 {         // path A job table
  int k0[48];
  int lo[48];          // 256-aligned support start
  int nch[48];         // number of 32-K chunks
  int cbase[48];       // prefix sum of nch
  int n;
  int total;
};

__device__ inline void atomAddF(float* p, float v) {
  __hip_atomic_fetch_add(p, v, __ATOMIC_RELAXED, __HIP_MEMORY_SCOPE_AGENT);
}

// ---- pre-pass: padded f16 audio ----
__global__ __launch_bounds__(256) void prep_x_kernel(
    const float* __restrict__ x, _Float16* __restrict__ xp,
    const int pad, const int xps) {
  const int halfx = xps >> 1;
  int gid = blockIdx.x * 256 + threadIdx.x;
  if (gid >= kB * halfx) return;
  const int b = gid / halfx;
  const int i = (gid - b * halfx) * 2;
  float v0 = 0.f, v1 = 0.f;
  const int e0 = i, e1 = i + 1;
  if (e0 >= pad && e0 < pad + kS) v0 = x[(size_t)b * kS + (e0 - pad)];
  if (e1 >= pad && e1 < pad + kS) v1 = x[(size_t)b * kS + (e1 - pad)];
  half2v h;
  h.x = (_Float16)v0;
  h.y = (_Float16)v1;
  *(half2v*)&xp[(size_t)b * xps + i] = h;
}

// ---- pre-pass: B fragments in MFMA lane order ----
// Layout per global chunk (32 K-cols): 2048 B = [64 lanes x 16B re][64 x 16B im]
__global__ __launch_bounds__(256) void prep_bpack_kernel(
    const float* __restrict__ kr, const float* __restrict__ ki,
    _Float16* __restrict__ bp, const int nmax, const Jobs2 jt) {
  const int gid = blockIdx.x * 256 + threadIdx.x;
  const int chunk = gid >> 6;
  const int lane = gid & 63;
  if (chunk >= jt.total) return;
  int jb = 0;
  #pragma unroll 1
  for (int j = 1; j < jt.n; ++j)
    if (chunk >= jt.cbase[j]) jb = j;
  const int c = chunk - jt.cbase[jb];
  const int q = lane >> 4;
  const int m = lane & 15;
  const int bin = jt.k0[jb] + m;
  const int ncol = jt.lo[jb] + c * 32 + q * 8;
  const bool binok = (bin < kBins);
  const float* rowr = kr + (size_t)bin * nmax;
  const float* rowi = ki + (size_t)bin * nmax;
  half8 hre, him;
  #pragma unroll
  for (int j = 0; j < 8; ++j) {
    const int col = ncol + j;
    const bool ok = binok && (col < nmax);
    hre[j] = ok ? (_Float16)(rowr[col] * kKScale) : (_Float16)0.f;
    him[j] = ok ? (_Float16)(rowi[col] * kKScale) : (_Float16)0.f;
  }
  _Float16* dst = bp + (size_t)chunk * 1024 + lane * 8;
  *(half8*)dst = hre;
  *(half8*)(dst + 512) = him;
}

// ---- path A main: barrier-free MFMA GEMM ----
__global__ __launch_bounds__(256) void cqt_mfma2_kernel(
    const _Float16* __restrict__ bp, const _Float16* __restrict__ xp,
    float* __restrict__ accb, const int xps, const Jobs2 jt) {
  const int jb = blockIdx.x;
  const int b  = blockIdx.z;
  const int fb = blockIdx.y;
  const int tid  = threadIdx.x;
  const int lane = tid & 63;
  const int wave = tid >> 6;
  const int m = lane & 15;
  const int q = lane >> 4;
  const int k0 = jt.k0[jb];
  const int fbase = fb * 256 + wave * 64;

  const _Float16* ax = xp + (size_t)b * xps +
                       (size_t)(fbase + m) * kHop + q * 8 + jt.lo[jb];
  const _Float16* bpc = bp + (size_t)jt.cbase[jb] * 1024 + lane * 8;
  const int nch = jt.nch[jb];

  floatx4 accr[4], acci[4];
  #pragma unroll
  for (int tl = 0; tl < 4; ++tl) {
    accr[tl] = (floatx4){0.f, 0.f, 0.f, 0.f};
    acci[tl] = (floatx4){0.f, 0.f, 0.f, 0.f};
  }

  #pragma unroll 2
  for (int c = 0; c < nch; ++c) {
    const half8 br = *(const half8*)(bpc + (size_t)c * 1024);
    const half8 bi = *(const half8*)(bpc + (size_t)c * 1024 + 512);
    const _Float16* ac = ax + c * 32;
    #pragma unroll
    for (int tl = 0; tl < 4; ++tl) {
      const half8 a = *(const half8*)(ac + tl * 16 * kHop);
      accr[tl] = __builtin_amdgcn_mfma_f32_16x16x32_f16(a, br, accr[tl], 0, 0, 0);
      acci[tl] = __builtin_amdgcn_mfma_f32_16x16x32_f16(a, bi, acci[tl], 0, 0, 0);
    }
  }

  #pragma unroll
  for (int tl = 0; tl < 4; ++tl) {
    #pragma unroll
    for (int r = 0; r < 4; ++r) {
      const int t = fbase + tl * 16 + q * 4 + r;
      const size_t o = (((size_t)b * kTPad + t) * kBinPad + (k0 + m)) * 2;
      atomAddF(&accb[o],     accr[tl][r] * kKScaleInv);
      atomAddF(&accb[o + 1], acci[tl][r] * kKScaleInv);
    }
  }
}

// ---- path B main: round-3 LDS-staging MFMA (verified) ----
__global__ __launch_bounds__(256) void cqt_mfma_kernel(
    const float* __restrict__ kr, const float* __restrict__ ki,
    const _Float16* __restrict__ xp, float* __restrict__ accb,
    const int nmax, const int xps, const Jobs jt) {
  __shared__ _Float16 Bs[2][16][264];
  const int jb = blockIdx.x;
  const int k0   = jt.k0[jb];
  const int n_lo = jt.lo[jb];
  const int n_hi = jt.hi[jb];
  const int b  = blockIdx.z;
  const int fb = blockIdx.y;
  const int tid  = threadIdx.x;
  const int lane = tid & 63;
  const int wave = tid >> 6;
  const int m = lane & 15;
  const int q = lane >> 4;
  const int sbin = tid >> 4;
  const int scol = tid & 15;
  const int gbin = k0 + sbin;
  const bool binok = (gbin < kBins);
  const float* rowr = kr + (size_t)gbin * nmax;
  const float* rowi = ki + (size_t)gbin * nmax;
  const int fbase = fb * 256 + wave * 64;
  const _Float16* ax =
      xp + (size_t)b * xps + (size_t)(fbase + m) * kHop + q * 8;
  floatx4 accr[4], acci[4];
  #pragma unroll
  for (int tl = 0; tl < 4; ++tl) {
    accr[tl] = (floatx4){0.f, 0.f, 0.f, 0.f};
    acci[tl] = (floatx4){0.f, 0.f, 0.f, 0.f};
  }
  for (int n0r = n_lo; n0r < n_hi; n0r += 256) {
    __syncthreads();
    #pragma unroll
    for (int c = 0; c < 16; ++c) {
      const int col = n0r + scol + c * 16;
      const bool ok = binok && (col < nmax);
      const float vr = ok ? rowr[col] : 0.f;
      const float vi = ok ? rowi[col] : 0.f;
      Bs[0][sbin][scol + c * 16] = (_Float16)(vr * kKScale);
      Bs[1][sbin][scol + c * 16] = (_Float16)(vi * kKScale);
    }
    __syncthreads();
    const _Float16* axr = ax + n0r;
    #pragma unroll
    for (int c = 0; c < 8; ++c) {
      const int ko = c * 32 + q * 8;
      const half8 br = *(const half8*)&Bs[0][m][ko];
      const half8 bi = *(const half8*)&Bs[1][m][ko];
      #pragma unroll
      for (int tl = 0; tl < 4; ++tl) {
        const half8 a = *(const half8*)(axr + tl * 16 * kHop + c * 32);
        accr[tl] = __builtin_amdgcn_mfma_f32_16x16x32_f16(a, br, accr[tl], 0, 0, 0);
        acci[tl] = __builtin_amdgcn_mfma_f32_16x16x32_f16(a, bi, acci[tl], 0, 0, 0);
      }
    }
  }
  #pragma unroll
  for (int tl = 0; tl < 4; ++tl) {
    #pragma unroll
    for (int r = 0; r < 4; ++r) {
      const int t = fbase + tl * 16 + q * 4 + r;
      const size_t o = (((size_t)b * kTPad + t) * kBinPad + (k0 + m)) * 2;
      atomAddF(&accb[o],     accr[tl][r] * kKScaleInv);
      atomAddF(&accb[o + 1], acci[tl][r] * kKScaleInv);
    }
  }
}

// ---- final: magnitude ----
__global__ __launch_bounds__(256) void cqt_mag_final(
    const float* __restrict__ accb, float* __restrict__ out) {
  int gid = blockIdx.x * 256 + threadIdx.x;
  if (gid >= kB * kT * kBins) return;
  const int k = gid % kBins;
  const int r = gid / kBins;
  const int t = r % kT;
  const int b = r / kT;
  const float2 v = ((const float2*)accb)[((size_t)b * kTPad + t) * kBinPad + k];
  out[gid] = sqrtf(v.x * v.x + v.y * v.y);
}

// ================= path C: verified fp32 kernel (round 2) =================
namespace fb32 {
constexpr int TT = 8;
constexpr int KG = 4;
constexpr int kTTiles  = (kT + TT - 1) / TT;
constexpr int kKGroups = kBins / KG;
constexpr int kWaves   = kB * kTTiles * kKGroups;
}

__global__ __launch_bounds__(256) void cqt_mag_kernel(
    const float* __restrict__ x,
    const float* __restrict__ kr,
    const float* __restrict__ ki,
    float* __restrict__ out,
    const int nmax, const int pad) {
  using namespace fb32;
  const int wave = (blockIdx.x << 2) + (threadIdx.x >> 6);
  const int lane = threadIdx.x & 63;
  if (wave >= kWaves) return;
  const int kg    = wave / (kB * kTTiles);
  const int rem   = wave - kg * (kB * kTTiles);
  const int b     = rem / kTTiles;
  const int ttile = rem - b * kTTiles;
  const int k0 = kg * KG;
  const int t0 = ttile * TT;
  const double Q  = 1.0 / (exp2(1.0 / 24.0) - 1.0);
  const double f0 = 32.7 * exp2((double)k0 / 24.0);
  int N = (int)ceil(Q * (double)kSR / f0) + 8;
  int full_start = nmax - N;
  if (full_start < 0) full_start = 0;
  int tbase[TT], lo[TT], t_last;
  { int t = t0 + TT - 1; if (t > kT - 1) t = kT - 1; t_last = t; }
  #pragma unroll
  for (int tt = 0; tt < TT; ++tt) {
    int t = t0 + tt; if (t > kT - 1) t = kT - 1;
    tbase[tt] = b * kS + t * kHop - pad;
    lo[tt]    = pad - t * kHop;
  }
  int head_start = pad - t_last * kHop;
  if (head_start < full_start) head_start = full_start;
  int safe = pad - t0 * kHop;
  if (safe < head_start) safe = head_start;
  int body_start = nmax - ((nmax - safe) & ~63);
  float accr[TT][KG], acci[TT][KG];
  #pragma unroll
  for (int tt = 0; tt < TT; ++tt)
    #pragma unroll
    for (int kk = 0; kk < KG; ++kk) { accr[tt][kk] = 0.f; acci[tt][kk] = 0.f; }
  for (int n = body_start - 64; n > head_start - 64; n -= 64) {
    const int nn = n + lane;
    const bool kok = (nn >= 0);
    float krv[KG], kiv[KG];
    #pragma unroll
    for (int kk = 0; kk < KG; ++kk) {
      krv[kk] = kok ? kr[(k0 + kk) * nmax + nn] : 0.f;
      kiv[kk] = kok ? ki[(k0 + kk) * nmax + nn] : 0.f;
    }
    float a[TT];
    #pragma unroll
    for (int tt = 0; tt < TT; ++tt)
      a[tt] = (nn >= lo[tt]) ? x[tbase[tt] + nn] : 0.f;
    #pragma unroll
    for (int tt = 0; tt < TT; ++tt)
      #pragma unroll
      for (int kk = 0; kk < KG; ++kk) {
        accr[tt][kk] = fmaf(a[tt], krv[kk], accr[tt][kk]);
        acci[tt][kk] = fmaf(a[tt], kiv[kk], acci[tt][kk]);
      }
  }
  for (int n = body_start; n < nmax; n += 64) {
    const int nn = n + lane;
    float krv[KG], kiv[KG];
    #pragma unroll
    for (int kk = 0; kk < KG; ++kk) {
      krv[kk] = kr[(k0 + kk) * nmax + nn];
      kiv[kk] = ki[(k0 + kk) * nmax + nn];
    }
    float a[TT];
    #pragma unroll
    for (int tt = 0; tt < TT; ++tt)
      a[tt] = x[tbase[tt] + nn];
    #pragma unroll
    for (int tt = 0; tt < TT; ++tt)
      #pragma unroll
      for (int kk = 0; kk < KG; ++kk) {
        accr[tt][kk] = fmaf(a[tt], krv[kk], accr[tt][kk]);
        acci[tt][kk] = fmaf(a[tt], kiv[kk], acci[tt][kk]);
      }
  }
  #pragma unroll
  for (int tt = 0; tt < TT; ++tt) {
    #pragma unroll
    for (int kk = 0; kk < KG; ++kk) {
      float r = accr[tt][kk];
      float i = acci[tt][kk];
      #pragma unroll
      for (int s = 32; s > 0; s >>= 1) {
        r += __shfl_xor(r, s, 64);
        i += __shfl_xor(i, s, 64);
      }
      if (lane == 0) {
        const int t = t0 + tt;
        if (t < kT)
          out[(b * kT + t) * kBins + (k0 + kk)] = sqrtf(r * r + i * i);
      }
    }
  }
}
// ============================================================================

extern "C" void kernel_launch(void* const* d_in, const int* in_sizes, int n_in,
                              void* d_out, int out_size, void* d_ws, size_t ws_size,
                              hipStream_t stream) {
  const float* x  = (const float*)d_in[0];   // [4, 1, 352768]
  const float* kr = (const float*)d_in[1];   // [168, nmax]
  const float* ki = (const float*)d_in[2];   // [168, nmax]
  float* out = (float*)d_out;                // [4, 1, 689, 168]

  const int nmax = in_sizes[1] / kBins;      // 23013 (runtime truth)
  const int pad  = nmax - kHop;

  const int kcap = ((nmax + 255) / 256) * 256;              // 23040
  const int xps  = (kTPad - 1) * kHop + kcap + 256;
  const size_t xp_bytes  = (size_t)kB * xps * sizeof(_Float16);
  const size_t acc_off   = (xp_bytes + 511) & ~(size_t)511;
  const size_t acc_bytes = (size_t)kB * kTPad * kBinPad * 2 * sizeof(float);
  const size_t bp_off    = (acc_off + acc_bytes + 511) & ~(size_t)511;

  const double Q = 1.0 / (exp2(1.0 / 24.0) - 1.0);

  // ---- path A job table: support-trimmed 2048-K slabs, 256-granular start ----
  Jobs2 j2;
  int nj2 = 0, tot = 0;
  for (int g = 0; g < 11; ++g) {
    const int gk0 = 16 * g;
    const double f0 = 32.7 * exp2((double)gk0 / 24.0);
    const int N = (int)ceil(Q * (double)kSR / f0) + 8;
    int lo_r = nmax - N;
    if (lo_r < 0) lo_r = 0;
    lo_r &= ~255;
    const int s0 = (lo_r / 2048) * 2048;
    for (int s = s0; s < kcap && nj2 < 48; s += 2048) {
      const int lo = (s < lo_r) ? lo_r : s;
      const int hi = (s + 2048 < kcap) ? s + 2048 : kcap;
      j2.k0[nj2]    = gk0;
      j2.lo[nj2]    = lo;
      j2.nch[nj2]   = (hi - lo) / 32;
      j2.cbase[nj2] = tot;
      tot += j2.nch[nj2];
      ++nj2;
    }
  }
  j2.n = nj2;       // 44 expected
  j2.total = tot;   // ~2650 chunks

  const size_t bp_bytes = (size_t)tot * 2048;
  const size_t ws_A = bp_off + bp_bytes;
  const size_t ws_B = acc_off + acc_bytes;

  if (ws_size >= ws_A) {
    // ---- path A ----
    _Float16* xp = (_Float16*)d_ws;
    float* accb  = (float*)((char*)d_ws + acc_off);
    _Float16* bp = (_Float16*)((char*)d_ws + bp_off);

    hipMemsetAsync(accb, 0, acc_bytes, stream);
    {
      const int total = kB * (xps / 2);
      prep_x_kernel<<<(total + 255) / 256, 256, 0, stream>>>(x, xp, pad, xps);
    }
    {
      const int threads = tot * 64;
      prep_bpack_kernel<<<(threads + 255) / 256, 256, 0, stream>>>(
          kr, ki, bp, nmax, j2);
    }
    {
      dim3 grid(nj2, kTPad / 256, kB);   // (44, 3, 4)
      cqt_mfma2_kernel<<<grid, 256, 0, stream>>>(bp, xp, accb, xps, j2);
    }
    {
      const int total = kB * kT * kBins;
      cqt_mag_final<<<(total + 255) / 256, 256, 0, stream>>>(accb, out);
    }
    return;
  }

  if (ws_size >= ws_B) {
    // ---- path B (round-3, verified ~224us) ----
    _Float16* xp = (_Float16*)d_ws;
    float* accb  = (float*)((char*)d_ws + acc_off);
    Jobs jt;
    int nj = 0;
    for (int g = 0; g < 11; ++g) {
      const int gk0 = 16 * g;
      const double f0 = 32.7 * exp2((double)gk0 / 24.0);
      const int N = (int)ceil(Q * (double)kSR / f0) + 8;
      int lo = nmax - N;
      if (lo < 0) lo = 0;
      lo = (lo / 2048) * 2048;
      for (int s = lo; s < kcap && nj < 48; s += 2048) {
        jt.k0[nj] = gk0;
        jt.lo[nj] = s;
        jt.hi[nj] = (s + 2048 < kcap) ? s + 2048 : kcap;
        ++nj;
      }
    }
    jt.n = nj;
    hipMemsetAsync(accb, 0, acc_bytes, stream);
    {
      const int total = kB * (xps / 2);
      prep_x_kernel<<<(total + 255) / 256, 256, 0, stream>>>(x, xp, pad, xps);
    }
    {
      dim3 grid(nj, kTPad / 256, kB);
      cqt_mfma_kernel<<<grid, 256, 0, stream>>>(kr, ki, xp, accb, nmax, xps, jt);
    }
    {
      const int total = kB * kT * kBins;
      cqt_mag_final<<<(total + 255) / 256, 256, 0, stream>>>(accb, out);
    }
    return;
  }

  // ---- path C: fp32 fallback ----
  {
    const int blocks = fb32::kWaves / 4;
    cqt_mag_kernel<<<blocks, 256, 0, stream>>>(x, kr, ki, out, nmax, pad);
  }
}